// Round 1
// baseline (335.014 us; speedup 1.0000x reference)
//
#include <hip/hip_runtime.h>

#define ROWS 4096
#define COLS 2048
#define NLEV 16
#define TEMP 100.0f
#define EPS  1e-6f

#define TPB 256            // threads per block = columns per block
#define ROWS_PER_BLOCK 32  // row-chunk per block

// d_ws layout: float bin_mass[COLS][NLEV]  (zeroed each launch via memset node)

__global__ __launch_bounds__(TPB) void quant_main_kernel(
    const float* __restrict__ weight,
    const float* __restrict__ w_min,
    const float* __restrict__ w_max,
    float* __restrict__ dequant,
    float* __restrict__ bin_mass)
{
    const int c  = blockIdx.x * TPB + threadIdx.x;   // column (coalesced)
    const int r0 = blockIdx.y * ROWS_PER_BLOCK;

    const float wmin = w_min[c];
    const float wmax = w_max[c];
    const float mn   = fminf(wmin, wmax - EPS);       // w_min_c
    const float mx   = fmaxf(wmax, mn + EPS);         // w_max_c
    const float rng  = mx - mn;
    const float inv_rng = 1.0f / (rng + EPS);

    float acc[NLEV];
#pragma unroll
    for (int l = 0; l < NLEV; ++l) acc[l] = 0.0f;

    const float* __restrict__ wp = weight  + (size_t)r0 * COLS + c;
    float* __restrict__       dq = dequant + (size_t)r0 * COLS + c;

    for (int r = 0; r < ROWS_PER_BLOCK; ++r) {
        const float w = wp[(size_t)r * COLS];
        const float x = (w - mn) * inv_rng;   // w_norm in ~(0,1)
        const float z = x * TEMP;             // scaled position

        // softmax over 16 levels; no max-subtraction needed:
        // nearest level has exp(-100*|x-q|) >= exp(-100/30) ~= 0.036,
        // far levels underflow to 0 harmlessly (same as ref to ~1e-7 rel).
        float p[NLEV];
        float s  = 0.0f;
        float ws = 0.0f;
#pragma unroll
        for (int l = 0; l < NLEV; ++l) {
            const float d = z - (TEMP * ((float)l / 15.0f));
            const float e = __expf(-fabsf(d));
            p[l] = e;
            s   += e;
            ws  += e * (float)l;
        }
        const float inv_s = 1.0f / s;
        const float wq = ws * inv_s * (1.0f / 15.0f);  // sum(p*q_l)/s
        dq[(size_t)r * COLS] = wq * rng + mn;

#pragma unroll
        for (int l = 0; l < NLEV; ++l) acc[l] += p[l] * inv_s;
    }

    float* bm = bin_mass + (size_t)c * NLEV;
#pragma unroll
    for (int l = 0; l < NLEV; ++l) atomicAdd(bm + l, acc[l]);
}

__global__ __launch_bounds__(256) void entropy_kernel(
    const float* __restrict__ bin_mass,
    float* __restrict__ out_ent)
{
    __shared__ float red[256];
    float ent = 0.0f;
    for (int c = threadIdx.x; c < COLS; c += 256) {
        const float* bm = bin_mass + (size_t)c * NLEV;
        float m[NLEV];
        float tot = 0.0f;
#pragma unroll
        for (int l = 0; l < NLEV; ++l) { m[l] = bm[l]; tot += m[l]; }
        const float inv = 1.0f / (tot + EPS);
#pragma unroll
        for (int l = 0; l < NLEV; ++l) {
            const float pr = m[l] * inv;
            ent -= pr * __logf(pr + EPS);
        }
    }
    red[threadIdx.x] = ent;
    __syncthreads();
#pragma unroll
    for (int off = 128; off > 0; off >>= 1) {
        if (threadIdx.x < off) red[threadIdx.x] += red[threadIdx.x + off];
        __syncthreads();
    }
    if (threadIdx.x == 0) out_ent[0] = red[0];
}

extern "C" void kernel_launch(void* const* d_in, const int* in_sizes, int n_in,
                              void* d_out, int out_size, void* d_ws, size_t ws_size,
                              hipStream_t stream)
{
    const float* weight = (const float*)d_in[0];
    const float* w_min  = (const float*)d_in[1];
    const float* w_max  = (const float*)d_in[2];

    float* out     = (float*)d_out;
    float* dequant = out;                          // ROWS*COLS floats
    float* out_ent = out + (size_t)ROWS * COLS;    // 1 float
    float* bin_mass = (float*)d_ws;                // COLS*NLEV floats

    // ws is re-poisoned (0xAA) before every timed launch -> must zero it here.
    hipMemsetAsync(d_ws, 0, (size_t)COLS * NLEV * sizeof(float), stream);

    dim3 grid(COLS / TPB, ROWS / ROWS_PER_BLOCK);  // (8, 128)
    quant_main_kernel<<<grid, TPB, 0, stream>>>(weight, w_min, w_max, dequant, bin_mass);

    entropy_kernel<<<1, 256, 0, stream>>>(bin_mass, out_ent);
}

// Round 2
// 123.833 us; speedup vs baseline: 2.7054x; 2.7054x over previous
//
#include <hip/hip_runtime.h>

#define ROWS 4096
#define COLS 2048
#define NLEV 16
#define TEMP 100.0f
#define EPS  1e-6f

#define TPB 256            // threads per block = columns per block
#define RPB 128            // rows per block
#define RBLKS (ROWS / RPB) // 32 row-blocks
#define UNROLL 8

// d_ws layout: float partial[RBLKS][COLS][NLEV]  = 32*2048*16*4 B = 4.2 MB

__global__ __launch_bounds__(TPB) void quant_main_kernel(
    const float* __restrict__ weight,
    const float* __restrict__ w_min,
    const float* __restrict__ w_max,
    float* __restrict__ dequant,
    float* __restrict__ partial)
{
    const int c  = blockIdx.x * TPB + threadIdx.x;   // column (coalesced)
    const int r0 = blockIdx.y * RPB;

    const float wmin = w_min[c];
    const float wmax = w_max[c];
    const float mn   = fminf(wmin, wmax - EPS);       // w_min_c
    const float mx   = fmaxf(wmax, mn + EPS);         // w_max_c
    const float rng  = mx - mn;
    const float inv_rng = 1.0f / (rng + EPS);

    float acc[NLEV];
#pragma unroll
    for (int l = 0; l < NLEV; ++l) acc[l] = 0.0f;

    const float* __restrict__ wp = weight  + (size_t)r0 * COLS + c;
    float* __restrict__       dq = dequant + (size_t)r0 * COLS + c;

    for (int r = 0; r < RPB; r += UNROLL) {
        // load phase: UNROLL independent coalesced loads in flight
        float w[UNROLL];
#pragma unroll
        for (int j = 0; j < UNROLL; ++j)
            w[j] = wp[(size_t)(r + j) * COLS];

#pragma unroll
        for (int j = 0; j < UNROLL; ++j) {
            const float x = (w[j] - mn) * inv_rng;   // w_norm in ~(0,1)
            const float z = x * TEMP;

            // softmax over 16 levels; no max-subtraction needed:
            // nearest level has exp >= e^-3.34, far levels underflow to 0.
            float p[NLEV];
            float s  = 0.0f;
            float ws = 0.0f;
#pragma unroll
            for (int l = 0; l < NLEV; ++l) {
                const float d = z - (TEMP * ((float)l / 15.0f));
                const float e = __expf(-fabsf(d));
                p[l] = e;
                s   += e;
                ws  += e * (float)l;
            }
            const float inv_s = 1.0f / s;
            dq[(size_t)(r + j) * COLS] = (ws * inv_s * (1.0f / 15.0f)) * rng + mn;
#pragma unroll
            for (int l = 0; l < NLEV; ++l) acc[l] += p[l] * inv_s;
        }
    }

    // plain coalesced partial write: wave writes 64*64B contiguous
    float* pp = partial + ((size_t)blockIdx.y * COLS + c) * NLEV;
#pragma unroll
    for (int l = 0; l < NLEV; ++l) pp[l] = acc[l];
}

__global__ __launch_bounds__(128) void entropy_kernel(
    const float* __restrict__ partial,
    float* __restrict__ out_ent)
{
    __shared__ float red[128];
    const int c = blockIdx.x * 128 + threadIdx.x;    // one thread per column

    float m[NLEV];
#pragma unroll
    for (int l = 0; l < NLEV; ++l) m[l] = 0.0f;

    for (int rb = 0; rb < RBLKS; ++rb) {
        const float4* pp = (const float4*)(partial + ((size_t)rb * COLS + c) * NLEV);
#pragma unroll
        for (int q = 0; q < NLEV / 4; ++q) {
            const float4 v = pp[q];
            m[q * 4 + 0] += v.x;
            m[q * 4 + 1] += v.y;
            m[q * 4 + 2] += v.z;
            m[q * 4 + 3] += v.w;
        }
    }

    float tot = 0.0f;
#pragma unroll
    for (int l = 0; l < NLEV; ++l) tot += m[l];
    const float inv = 1.0f / (tot + EPS);

    float ent = 0.0f;
#pragma unroll
    for (int l = 0; l < NLEV; ++l) {
        const float pr = m[l] * inv;
        ent -= pr * __logf(pr + EPS);
    }

    red[threadIdx.x] = ent;
    __syncthreads();
#pragma unroll
    for (int off = 64; off > 0; off >>= 1) {
        if (threadIdx.x < off) red[threadIdx.x] += red[threadIdx.x + off];
        __syncthreads();
    }
    if (threadIdx.x == 0) atomicAdd(out_ent, red[0]);  // 16 atomics total
}

extern "C" void kernel_launch(void* const* d_in, const int* in_sizes, int n_in,
                              void* d_out, int out_size, void* d_ws, size_t ws_size,
                              hipStream_t stream)
{
    const float* weight = (const float*)d_in[0];
    const float* w_min  = (const float*)d_in[1];
    const float* w_max  = (const float*)d_in[2];

    float* out     = (float*)d_out;
    float* dequant = out;                          // ROWS*COLS floats
    float* out_ent = out + (size_t)ROWS * COLS;    // 1 float
    float* partial = (float*)d_ws;                 // RBLKS*COLS*NLEV floats

    // zero only the scalar entropy slot (d_out is re-poisoned each call)
    hipMemsetAsync(out_ent, 0, sizeof(float), stream);

    dim3 grid(COLS / TPB, ROWS / RPB);             // (8, 32)
    quant_main_kernel<<<grid, TPB, 0, stream>>>(weight, w_min, w_max, dequant, partial);

    entropy_kernel<<<COLS / 128, 128, 0, stream>>>(partial, out_ent);
}